// Round 15
// baseline (58.831 us; speedup 1.0000x reference)
//
#include <hip/hip_runtime.h>
#include <math.h>

// DeepFeatureLoss: B=2, N=4096, D=32, fp32 in/out.
// out[0..1] = ce_loss[b], out[2..3] = reg_loss[b].
//
// ce_i = log(s_f) - t/s_p  (softmax max pinned at 0; dists <= 0):
//   s_p = sum_j exp(pd_ij), t = sum_j exp(pd_ij)*fd_ij, s_f = sum_j exp(fd_ij)
// exp2 units throughout; t *= LN2 at finalize.
//
// R15: sparsity WITHOUT branches (R14 lesson: branch-in-loop + launches
// cost more than skipped work). Split by kernel:
//  kB: PURE feature path (strict deletion from R12): bfrag + n2 scalar,
//      C-fold MFMA -> fd', exp2 -> sf. ~16 VALU + 8 trans / iter.
//  kH/kN: 32^3 cell hash -> explicit near-pair list (d2<=7.8e-4, ep>=2^-45;
//      ~11K pairs of 33.5M). Self-pair unconditional -> sp>=1.
//  kP: per pair fp32 dot -> ep, fd'; atomicAdd sp/t planes.
//  k2: ce = log(sf) - (t*LN2)/sp, + reg reduction.
//
// ws (floats): n1n[0,8192) n2p[8192,16384) fragB[16384,147456)
// fragA[147456,278528) regp[278528,286720) sfp[286720,303104)
// spP[303104,311296) tP[311296,319488) counts[319488,385024)
// buckets[385024,647168) pairs[647168,679936) pairCnt[679936).

#define NPTS 4096
#define ROWS_TOT 8192
#define DF 32

#define L2E  1.4426950408889634f
#define LN2  0.6931471805599453f
#define FSC  1.6986436f          // sqrt(2*log2e)
#define NCELL 32
#define CAP 8
#define D2THR 7.797e-4f          // keep pairs with log2e*(d/sigma)^2 <= 45
#define EPSC 57707.80f           // log2e / sigma^2
#define MAXP 32768

typedef _Float16 half8 __attribute__((ext_vector_type(8)));
typedef float f4 __attribute__((ext_vector_type(4)));

static __device__ __forceinline__ int cell_of(float x, float y, float z) {
    int cx = min(NCELL - 1, max(0, (int)(x * NCELL)));
    int cy = min(NCELL - 1, max(0, (int)(y * NCELL)));
    int cz = min(NCELL - 1, max(0, (int)(z * NCELL)));
    return (cz * NCELL + cy) * NCELL + cx;
}

// ---- kA: fragments + norm planes + reg + zeroing ----
__global__ void kA_prep(const float* __restrict__ pts,
                        const float* __restrict__ f1g,
                        const float* __restrict__ f2g,
                        float* __restrict__ n1n, float* __restrict__ n2p,
                        _Float16* __restrict__ fragA, _Float16* __restrict__ fragB,
                        float* __restrict__ regp,
                        float* __restrict__ spP, float* __restrict__ tP,
                        unsigned* __restrict__ counts, unsigned* __restrict__ pairCnt,
                        float* __restrict__ out) {
    const int r = blockIdx.x * 64 + threadIdx.x;     // 0..8191
    if (r < 4) out[r] = 0.0f;
    if (r == 0) pairCnt[0] = 0u;
    spP[r] = 0.0f; tP[r] = 0.0f;
#pragma unroll
    for (int k = 0; k < 8; ++k) counts[r + k * ROWS_TOT] = 0u;  // 65536
    const int jt = r >> 4;
    const int c  = r & 15;

    float n1, n2, reg1, reg2;
    {
        const float4* f2v = (const float4*)(f2g + (size_t)r * DF);
        float vals[32]; float s = 0.0f;
#pragma unroll
        for (int q = 0; q < 8; ++q) {
            float4 v = f2v[q];
            vals[4*q]=v.x; vals[4*q+1]=v.y; vals[4*q+2]=v.z; vals[4*q+3]=v.w;
            s += v.x*v.x + v.y*v.y + v.z*v.z + v.w*v.w;
        }
        n2 = s;
        reg2 = s - vals[0]*vals[0] - vals[1]*vals[1] - vals[2]*vals[2];
        half8* fv = (half8*)fragB;
#pragma unroll
        for (int kb = 0; kb < 4; ++kb) {
            half8 h;
#pragma unroll
            for (int i = 0; i < 8; ++i) h[i] = (_Float16)(vals[kb*8+i] * FSC);
            fv[(size_t)jt*64 + kb*16 + c] = h;
        }
    }
    {
        const float4* f1v = (const float4*)(f1g + (size_t)r * DF);
        float vals[32]; float s = 0.0f;
#pragma unroll
        for (int q = 0; q < 8; ++q) {
            float4 v = f1v[q];
            vals[4*q]=v.x; vals[4*q+1]=v.y; vals[4*q+2]=v.z; vals[4*q+3]=v.w;
            s += v.x*v.x + v.y*v.y + v.z*v.z + v.w*v.w;
        }
        n1 = s;
        reg1 = s - vals[0]*vals[0] - vals[1]*vals[1] - vals[2]*vals[2];
        half8* fv = (half8*)fragA;
#pragma unroll
        for (int kb = 0; kb < 4; ++kb) {
            half8 h;
#pragma unroll
            for (int i = 0; i < 8; ++i) h[i] = (_Float16)(vals[kb*8+i] * FSC);
            fv[(size_t)jt*64 + kb*16 + c] = h;
        }
    }
    n1n[r] = -(n1 * L2E);                            // negated row norm
    n2p[r] =  (n2 * L2E);                            // positive col norm
    regp[r] = reg1 + reg2;
}

// ---- kH: bucket points ----
__global__ void kH_hash(const float* __restrict__ pts,
                        unsigned* __restrict__ counts,
                        unsigned short* __restrict__ buckets) {
    const int r = blockIdx.x * 64 + threadIdx.x;
    const int b = r >> 12, il = r & (NPTS - 1);
    const float* p = pts + (size_t)r * 3;
    const int cell = cell_of(p[0], p[1], p[2]);
    const unsigned old = atomicAdd(&counts[b * 32768 + cell], 1u);
    if (old < CAP) buckets[(size_t)(b * 32768 + cell) * CAP + old] = (unsigned short)il;
}

// ---- kN: neighbor scan -> pair list (gi 13b | gj 13b) ----
__global__ void kN_pairs(const float* __restrict__ pts,
                         const unsigned* __restrict__ counts,
                         const unsigned short* __restrict__ buckets,
                         unsigned* __restrict__ pairs,
                         unsigned* __restrict__ pairCnt) {
    const int r = blockIdx.x * 64 + threadIdx.x;     // global row = gi
    const int b = r >> 12, il = r & (NPTS - 1);
    {   // self pair, unconditional
        const unsigned idx = atomicAdd(pairCnt, 1u);
        if (idx < MAXP) pairs[idx] = ((unsigned)r << 13) | (unsigned)r;
    }
    const float* p = pts + (size_t)r * 3;
    const float px = p[0], py = p[1], pz = p[2];
    const int cx = min(NCELL-1, max(0, (int)(px * NCELL)));
    const int cy = min(NCELL-1, max(0, (int)(py * NCELL)));
    const int cz = min(NCELL-1, max(0, (int)(pz * NCELL)));
    const float* ptsb = pts + (size_t)b * NPTS * 3;

    for (int dz = -1; dz <= 1; ++dz) {
        const int z = cz + dz; if (z < 0 || z >= NCELL) continue;
        for (int dy = -1; dy <= 1; ++dy) {
            const int y = cy + dy; if (y < 0 || y >= NCELL) continue;
            for (int dx = -1; dx <= 1; ++dx) {
                const int x = cx + dx; if (x < 0 || x >= NCELL) continue;
                const int cell = (z * NCELL + y) * NCELL + x;
                const unsigned cnt = min(counts[b * 32768 + cell], (unsigned)CAP);
                for (unsigned e = 0; e < cnt; ++e) {
                    const int j = buckets[(size_t)(b * 32768 + cell) * CAP + e];
                    if (j == il) continue;           // self handled above
                    const float ax = px - ptsb[(size_t)j*3];
                    const float ay = py - ptsb[(size_t)j*3+1];
                    const float az = pz - ptsb[(size_t)j*3+2];
                    const float d2 = ax*ax + ay*ay + az*az;
                    if (d2 <= D2THR) {
                        const unsigned gj = (unsigned)(b * NPTS + j);
                        const unsigned idx = atomicAdd(pairCnt, 1u);
                        if (idx < MAXP) pairs[idx] = ((unsigned)r << 13) | gj;
                    }
                }
            }
        }
    }
}

// ---- kP: sparse point path: ep, fd' -> sp/t planes ----
__global__ void kP_sparse(const float* __restrict__ pts,
                          const float* __restrict__ f1g,
                          const float* __restrict__ f2g,
                          const float* __restrict__ n1n,
                          const float* __restrict__ n2p,
                          const unsigned* __restrict__ pairs,
                          const unsigned* __restrict__ pairCnt,
                          float* __restrict__ spP, float* __restrict__ tP) {
    const unsigned t = blockIdx.x * 256 + threadIdx.x;
    const unsigned cnt = min(pairCnt[0], (unsigned)MAXP);
    if (t >= cnt) return;
    const unsigned pr = pairs[t];
    const int gi = pr >> 13, gj = pr & 8191;

    const float* pi = pts + (size_t)gi * 3;
    const float* pj = pts + (size_t)gj * 3;
    const float ax = pi[0]-pj[0], ay = pi[1]-pj[1], az = pi[2]-pj[2];
    const float d2 = ax*ax + ay*ay + az*az;
    const float ep = __builtin_amdgcn_exp2f(-d2 * EPSC);

    const float4* a4 = (const float4*)(f1g + (size_t)gi * DF);
    const float4* b4 = (const float4*)(f2g + (size_t)gj * DF);
    float dot = 0.0f;
#pragma unroll
    for (int q = 0; q < 8; ++q) {
        const float4 av = a4[q], bv = b4[q];
        dot += av.x*bv.x + av.y*bv.y + av.z*bv.z + av.w*bv.w;
    }
    // fd' = 2*L2E*dot - n1' - n2' = 2*L2E*dot + n1n[gi] - n2p[gj]
    const float fd = fmaf(2.0f * L2E, dot, n1n[gi] - n2p[gj]);
    atomicAdd(&spP[gi], ep);
    atomicAdd(&tP[gi], ep * fd);
}

// ---- kB: dense feature-only (R12 MI=2 minus point path) ----
__launch_bounds__(512)
__global__ void kB_main(const float* __restrict__ n1n,
                        const float* __restrict__ n2p,
                        const _Float16* __restrict__ fragA,
                        const _Float16* __restrict__ fragB,
                        float* __restrict__ sfp) {
    __shared__ float sF[8][32];

    const int tid = threadIdx.x;
    const int l = tid & 63, wv = tid >> 6;           // wave 0..7
    const int ip = blockIdx.x >> 1;                  // i-pair 0..255
    const int jh = blockIdx.x & 1;                   // j-half 0/1
    const int b  = ip >> 7;
    const int i0g = ip * 32;
    const int lr = l & 15, lk = l >> 4;

    const half8 afA = ((const half8*)fragA)[(size_t)(ip * 2)     * 64 + l];
    const half8 afB = ((const half8*)fragA)[(size_t)(ip * 2 + 1) * 64 + l];

    const int rbA = i0g + lk * 4;
    const int rbB = i0g + 16 + lk * 4;
    f4 qwA, qwB;                                     // -n1' per row
#pragma unroll
    for (int e = 0; e < 4; ++e) {
        qwA[e] = n1n[rbA + e];
        qwB[e] = n1n[rbB + e];
    }

    const int jt0 = b * 256 + jh * 128 + wv * 16;
    const int j0  = b * NPTS + jh * 2048 + wv * 256 + lr;
    const half8* fbase = (const half8*)fragB + ((size_t)jt0 * 64 + l);
    const float* nbase = n2p + j0;

    f4 sfA = {0,0,0,0}, sfB = {0,0,0,0};

    half8 bfC = fbase[0];
    float n2C = nbase[0];
#pragma unroll
    for (int t = 0; t < 16; ++t) {
        half8 bfN = bfC;
        float n2N = n2C;
        if (t < 15) {                                // 1-deep prefetch
            bfN = fbase[(t + 1) * 64];
            n2N = nbase[(t + 1) * 16];
        }
        const f4 C1A = qwA - n2C;                    // -(n1'+n2')
        const f4 C1B = qwB - n2C;
        const f4 fdA = __builtin_amdgcn_mfma_f32_16x16x32_f16(afA, bfC, C1A, 0, 0, 0);
        const f4 fdB = __builtin_amdgcn_mfma_f32_16x16x32_f16(afB, bfC, C1B, 0, 0, 0);
#pragma unroll
        for (int e = 0; e < 4; ++e) {
            sfA[e] += __builtin_amdgcn_exp2f(fdA[e]);
            sfB[e] += __builtin_amdgcn_exp2f(fdB[e]);
        }
        bfC = bfN;
        n2C = n2N;
    }

#pragma unroll
    for (int m = 1; m < 16; m <<= 1) {
#pragma unroll
        for (int e = 0; e < 4; ++e) {
            sfA[e] += __shfl_xor(sfA[e], m);
            sfB[e] += __shfl_xor(sfB[e], m);
        }
    }
    if (lr == 0) {
#pragma unroll
        for (int e = 0; e < 4; ++e) {
            sF[wv][lk * 4 + e]      = sfA[e];
            sF[wv][16 + lk * 4 + e] = sfB[e];
        }
    }
    __syncthreads();

    if (tid < 32) {
        float sf_ = 0.f;
#pragma unroll
        for (int w = 0; w < 8; ++w) sf_ += sF[w][tid];
        sfp[(size_t)jh * ROWS_TOT + i0g + tid] = sf_;
    }
}

// ---- k2: finalize ----
__global__ void k2_final(const float* __restrict__ sfp,
                         const float* __restrict__ spP,
                         const float* __restrict__ tP,
                         const float* __restrict__ regp,
                         const float* __restrict__ wg,
                         float* __restrict__ out) {
    __shared__ float redc[4], redr[4];
    const int tid = threadIdx.x;
    const int r = blockIdx.x * 256 + tid;
    const int b = r >> 12;

    const float sf_ = sfp[r] + sfp[ROWS_TOT + r];
    const float sp_ = spP[r];
    const float tp_ = tP[r];
    const float ce = __logf(sf_) - (tp_ * LN2) / sp_;
    float contrib = wg[r] * ce;
    float rr = regp[r];

#pragma unroll
    for (int off = 32; off > 0; off >>= 1) {
        contrib += __shfl_down(contrib, off);
        rr      += __shfl_down(rr, off);
    }
    const int wave = tid >> 6, lane = tid & 63;
    if (lane == 0) { redc[wave] = contrib; redr[wave] = rr; }
    __syncthreads();
    if (tid == 0) {
        atomicAdd(&out[b],     redc[0] + redc[1] + redc[2] + redc[3]);
        atomicAdd(&out[2 + b], (redr[0] + redr[1] + redr[2] + redr[3])
                               * (1.0f / (29.0f * (float)NPTS)));
    }
}

extern "C" void kernel_launch(void* const* d_in, const int* in_sizes, int n_in,
                              void* d_out, int out_size, void* d_ws, size_t ws_size,
                              hipStream_t stream) {
    const float* pts = (const float*)d_in[0];
    const float* f1  = (const float*)d_in[1];
    const float* f2  = (const float*)d_in[2];
    const float* wg  = (const float*)d_in[3];
    float* out = (float*)d_out;

    float* ws = (float*)d_ws;
    float*          n1n    = ws;                           // 8192
    float*          n2p    = ws + 8192;                    // 8192
    _Float16*       fragB  = (_Float16*)(ws + 16384);      // 262144 halves
    _Float16*       fragA  = (_Float16*)(ws + 147456);     // 262144 halves
    float*          regp   = ws + 278528;                  // 8192
    float*          sfp    = ws + 286720;                  // 16384
    float*          spP    = ws + 303104;                  // 8192
    float*          tP     = ws + 311296;                  // 8192
    unsigned*       counts = (unsigned*)(ws + 319488);     // 65536
    unsigned short* buckets= (unsigned short*)(ws + 385024); // 524288 u16
    unsigned*       pairs  = (unsigned*)(ws + 647168);     // 32768
    unsigned*       pairCnt= (unsigned*)(ws + 679936);     // 1

    kA_prep<<<ROWS_TOT / 64, 64, 0, stream>>>(pts, f1, f2, n1n, n2p,
                                              fragA, fragB, regp,
                                              spP, tP, counts, pairCnt, out);
    kH_hash<<<ROWS_TOT / 64, 64, 0, stream>>>(pts, counts, buckets);
    kN_pairs<<<ROWS_TOT / 64, 64, 0, stream>>>(pts, counts, buckets, pairs, pairCnt);
    kB_main<<<512, 512, 0, stream>>>(n1n, n2p, fragA, fragB, sfp);
    kP_sparse<<<MAXP / 256, 256, 0, stream>>>(pts, f1, f2, n1n, n2p,
                                              pairs, pairCnt, spP, tP);
    k2_final<<<ROWS_TOT / 256, 256, 0, stream>>>(sfp, spP, tP, regp, wg, out);
}

// Round 16
// 57.936 us; speedup vs baseline: 1.0155x; 1.0155x over previous
//
#include <hip/hip_runtime.h>
#include <math.h>

// DeepFeatureLoss: B=2, N=4096, D=32, fp32 in/out.
// out[0..1] = ce_loss[b], out[2..3] = reg_loss[b].
//
// ce_i = log(s_f) - t/s_p  (softmax max pinned at 0; dists <= 0):
//   s_p = sum_j exp(pd_ij), t = sum_j exp(pd_ij)*fd_ij, s_f = sum_j exp(fd_ij)
// exp2 units; t *= LN2 at finalize.
//
// R16: sparsity with NO hash machinery (R15 lesson: latency-bound helper
// kernels ate the win). 3 launches:
//  kA: fragments (lane-ordered f16), n1n=-n1*L2E, n2p=n2*L2E,
//      pp2=(p*PSC, n2*L2E), regp; zero out.
//  kB: dense feature-only (R15's proven loop): C-fold MFMA -> fd', exp2,
//      sf. MI=2, 16 iters/wave.
//  k2: per 8-row block stage batch pts (64KB LDS float4); 32 lanes/row
//      brute-scan 4096 j: d2' = |dp*PSC|^2 (= exp2 arg directly);
//      hit d2'<=45 (~2.75/row, self incl. at d2=0) -> fp32 feature dot,
//      sp/t accumulate; width-32 shfl reduce; ce + reg -> out.
//      Dropped pairs: ep < 2^-45, invisible in fp32 (sp>=1).
//
// ws (floats): n1n[0,8192) n2p[8192,16384) pp2[16384,49152)
// fragB[49152,180224) fragA[180224,311296) regp[311296,319488)
// sfp[319488,335872).

#define NPTS 4096
#define ROWS_TOT 8192
#define DF 32

#define L2E  1.4426950408889634f
#define LN2  0.6931471805599453f
#define FSC  1.6986436f          // sqrt(2*log2e)
#define PSC  240.2244f           // 200*sqrt(log2e)
#define D2MAX 45.0f              // keep pairs with log2e*(d/sigma)^2 <= 45

typedef _Float16 half8 __attribute__((ext_vector_type(8)));
typedef float f4 __attribute__((ext_vector_type(4)));

// ---- kA: prep ----
__global__ void kA_prep(const float* __restrict__ pts,
                        const float* __restrict__ f1g,
                        const float* __restrict__ f2g,
                        float* __restrict__ n1n, float* __restrict__ n2p,
                        float* __restrict__ pp2,
                        _Float16* __restrict__ fragA, _Float16* __restrict__ fragB,
                        float* __restrict__ regp, float* __restrict__ out) {
    const int r = blockIdx.x * 64 + threadIdx.x;     // 0..8191
    if (r < 4) out[r] = 0.0f;
    const int jt = r >> 4;                           // global tile id 0..511
    const int c  = r & 15;                           // row/col within tile

    float n1, n2, reg1, reg2;
    {
        const float4* f2v = (const float4*)(f2g + (size_t)r * DF);
        float vals[32]; float s = 0.0f;
#pragma unroll
        for (int q = 0; q < 8; ++q) {
            float4 v = f2v[q];
            vals[4*q]=v.x; vals[4*q+1]=v.y; vals[4*q+2]=v.z; vals[4*q+3]=v.w;
            s += v.x*v.x + v.y*v.y + v.z*v.z + v.w*v.w;
        }
        n2 = s;
        reg2 = s - vals[0]*vals[0] - vals[1]*vals[1] - vals[2]*vals[2];
        half8* fv = (half8*)fragB;
#pragma unroll
        for (int kb = 0; kb < 4; ++kb) {             // lane-ordered slot
            half8 h;
#pragma unroll
            for (int i = 0; i < 8; ++i) h[i] = (_Float16)(vals[kb*8+i] * FSC);
            fv[(size_t)jt*64 + kb*16 + c] = h;
        }
    }
    {
        const float4* f1v = (const float4*)(f1g + (size_t)r * DF);
        float vals[32]; float s = 0.0f;
#pragma unroll
        for (int q = 0; q < 8; ++q) {
            float4 v = f1v[q];
            vals[4*q]=v.x; vals[4*q+1]=v.y; vals[4*q+2]=v.z; vals[4*q+3]=v.w;
            s += v.x*v.x + v.y*v.y + v.z*v.z + v.w*v.w;
        }
        n1 = s;
        reg1 = s - vals[0]*vals[0] - vals[1]*vals[1] - vals[2]*vals[2];
        half8* fv = (half8*)fragA;
#pragma unroll
        for (int kb = 0; kb < 4; ++kb) {
            half8 h;
#pragma unroll
            for (int i = 0; i < 8; ++i) h[i] = (_Float16)(vals[kb*8+i] * FSC);
            fv[(size_t)jt*64 + kb*16 + c] = h;
        }
    }
    const float* pp = pts + (size_t)r * 3;
    const float px = pp[0]*PSC, py = pp[1]*PSC, pz = pp[2]*PSC;
    n1n[r] = -(n1 * L2E);
    n2p[r] =  (n2 * L2E);
    ((float4*)pp2)[r] = make_float4(px, py, pz, n2 * L2E);
    regp[r] = reg1 + reg2;
}

// ---- kB: dense feature-only (R15's proven loop, MI=2) ----
__launch_bounds__(512)
__global__ void kB_main(const float* __restrict__ n1n,
                        const float* __restrict__ n2p,
                        const _Float16* __restrict__ fragA,
                        const _Float16* __restrict__ fragB,
                        float* __restrict__ sfp) {
    __shared__ float sF[8][32];

    const int tid = threadIdx.x;
    const int l = tid & 63, wv = tid >> 6;           // wave 0..7
    const int ip = blockIdx.x >> 1;                  // i-pair 0..255
    const int jh = blockIdx.x & 1;                   // j-half 0/1
    const int b  = ip >> 7;
    const int i0g = ip * 32;
    const int lr = l & 15, lk = l >> 4;

    const half8 afA = ((const half8*)fragA)[(size_t)(ip * 2)     * 64 + l];
    const half8 afB = ((const half8*)fragA)[(size_t)(ip * 2 + 1) * 64 + l];

    const int rbA = i0g + lk * 4;
    const int rbB = i0g + 16 + lk * 4;
    f4 qwA, qwB;                                     // -n1' per row
#pragma unroll
    for (int e = 0; e < 4; ++e) {
        qwA[e] = n1n[rbA + e];
        qwB[e] = n1n[rbB + e];
    }

    const int jt0 = b * 256 + jh * 128 + wv * 16;
    const int j0  = b * NPTS + jh * 2048 + wv * 256 + lr;
    const half8* fbase = (const half8*)fragB + ((size_t)jt0 * 64 + l);
    const float* nbase = n2p + j0;

    f4 sfA = {0,0,0,0}, sfB = {0,0,0,0};

    half8 bfC = fbase[0];
    float n2C = nbase[0];
#pragma unroll
    for (int t = 0; t < 16; ++t) {
        half8 bfN = bfC;
        float n2N = n2C;
        if (t < 15) {                                // 1-deep prefetch
            bfN = fbase[(t + 1) * 64];
            n2N = nbase[(t + 1) * 16];
        }
        const f4 C1A = qwA - n2C;                    // -(n1'+n2')
        const f4 C1B = qwB - n2C;
        const f4 fdA = __builtin_amdgcn_mfma_f32_16x16x32_f16(afA, bfC, C1A, 0, 0, 0);
        const f4 fdB = __builtin_amdgcn_mfma_f32_16x16x32_f16(afB, bfC, C1B, 0, 0, 0);
#pragma unroll
        for (int e = 0; e < 4; ++e) {
            sfA[e] += __builtin_amdgcn_exp2f(fdA[e]);
            sfB[e] += __builtin_amdgcn_exp2f(fdB[e]);
        }
        bfC = bfN;
        n2C = n2N;
    }

#pragma unroll
    for (int m = 1; m < 16; m <<= 1) {
#pragma unroll
        for (int e = 0; e < 4; ++e) {
            sfA[e] += __shfl_xor(sfA[e], m);
            sfB[e] += __shfl_xor(sfB[e], m);
        }
    }
    if (lr == 0) {
#pragma unroll
        for (int e = 0; e < 4; ++e) {
            sF[wv][lk * 4 + e]      = sfA[e];
            sF[wv][16 + lk * 4 + e] = sfB[e];
        }
    }
    __syncthreads();

    if (tid < 32) {
        float sf_ = 0.f;
#pragma unroll
        for (int w = 0; w < 8; ++w) sf_ += sF[w][tid];
        sfp[(size_t)jh * ROWS_TOT + i0g + tid] = sf_;
    }
}

// ---- k2: LDS brute scan for point path + finalize ----
__launch_bounds__(256)
__global__ void k2_scan(const float* __restrict__ pp2,
                        const float* __restrict__ f1g,
                        const float* __restrict__ f2g,
                        const float* __restrict__ n1n,
                        const float* __restrict__ sfp,
                        const float* __restrict__ regp,
                        const float* __restrict__ wg,
                        float* __restrict__ out) {
    __shared__ float4 P[NPTS];                       // 64 KB: batch pts + n2'
    __shared__ float redc[8], redr[8];

    const int tid = threadIdx.x;
    const int rowbase = blockIdx.x * 8;              // 8 rows per block
    const int b = rowbase >> 12;
    const int base = b * NPTS;

    const float4* pv = (const float4*)pp2 + base;
#pragma unroll
    for (int k = 0; k < 16; ++k)
        P[k * 256 + tid] = pv[k * 256 + tid];
    __syncthreads();

    const int row = rowbase + (tid >> 5);            // this group's row
    const int sub = tid & 31;
    const float4 q = P[row & (NPTS - 1)];
    const float n1r = n1n[row];
    const float4* f1v = (const float4*)(f1g + (size_t)row * DF);

    float sp = 0.0f, tt = 0.0f;
#pragma unroll 4
    for (int jj = sub; jj < NPTS; jj += 32) {
        const float4 v = P[jj];
        const float dx = q.x - v.x, dy = q.y - v.y, dz = q.z - v.z;
        const float d2 = fmaf(dx, dx, fmaf(dy, dy, dz * dz));
        if (d2 <= D2MAX) {                           // ~2.75 hits/row incl self
            const float ep = __builtin_amdgcn_exp2f(-d2);
            const float4* f2v = (const float4*)(f2g + (size_t)(base + jj) * DF);
            float dot = 0.0f;
#pragma unroll
            for (int qq = 0; qq < 8; ++qq) {
                const float4 a = f1v[qq], c = f2v[qq];
                dot += a.x*c.x + a.y*c.y + a.z*c.z + a.w*c.w;
            }
            const float fd = fmaf(2.0f * L2E, dot, n1r - v.w);
            sp += ep;
            tt = fmaf(ep, fd, tt);
        }
    }

#pragma unroll
    for (int m = 1; m < 32; m <<= 1) {
        sp += __shfl_xor(sp, m, 32);
        tt += __shfl_xor(tt, m, 32);
    }
    if (sub == 0) {
        const float sf_ = sfp[row] + sfp[ROWS_TOT + row];
        const float ce = __logf(sf_) - (tt * LN2) / sp;
        redc[tid >> 5] = wg[row] * ce;
        redr[tid >> 5] = regp[row];
    }
    __syncthreads();
    if (tid == 0) {
        float c = 0.f, rr = 0.f;
#pragma unroll
        for (int w = 0; w < 8; ++w) { c += redc[w]; rr += redr[w]; }
        atomicAdd(&out[b],     c);
        atomicAdd(&out[2 + b], rr * (1.0f / (29.0f * (float)NPTS)));
    }
}

extern "C" void kernel_launch(void* const* d_in, const int* in_sizes, int n_in,
                              void* d_out, int out_size, void* d_ws, size_t ws_size,
                              hipStream_t stream) {
    const float* pts = (const float*)d_in[0];
    const float* f1  = (const float*)d_in[1];
    const float* f2  = (const float*)d_in[2];
    const float* wg  = (const float*)d_in[3];
    float* out = (float*)d_out;

    float* ws = (float*)d_ws;
    float*     n1n   = ws;                           // 8192
    float*     n2p   = ws + 8192;                    // 8192
    float*     pp2   = ws + 16384;                   // 32768 (float4 x 8192)
    _Float16*  fragB = (_Float16*)(ws + 49152);      // 262144 halves
    _Float16*  fragA = (_Float16*)(ws + 180224);     // 262144 halves
    float*     regp  = ws + 311296;                  // 8192
    float*     sfp   = ws + 319488;                  // 16384

    kA_prep<<<ROWS_TOT / 64, 64, 0, stream>>>(pts, f1, f2, n1n, n2p, pp2,
                                              fragA, fragB, regp, out);
    kB_main<<<512, 512, 0, stream>>>(n1n, n2p, fragA, fragB, sfp);
    k2_scan<<<ROWS_TOT / 8, 256, 0, stream>>>(pp2, f1, f2, n1n, sfp, regp, wg, out);
}

// Round 17
// 40.185 us; speedup vs baseline: 1.4640x; 1.4418x over previous
//
#include <hip/hip_runtime.h>
#include <math.h>

// DeepFeatureLoss: B=2, N=4096, D=32, fp32 in/out.
// out[0..1] = ce_loss[b], out[2..3] = reg_loss[b].
//
// ce_i = log(s_f) - t/s_p  (softmax max pinned at 0; dists <= 0):
//   s_p = sum_j exp(pd_ij), t = sum_j exp(pd_ij)*fd_ij, s_f = sum_j exp(fd_ij)
// exp2 units; t *= LN2 at finalize.
//
// R17: dense feature path (proven ~10us) + point path as PHASE 2 of the
// SAME kB block (no extra launch, no LDS, no per-iter branch in phase 1):
//  phase1: C-fold MFMA -> fd', exp2 -> sf  (R15/R16 loop, unchanged).
//  phase2: 16 groups x 32 lanes; group owns 2 rows; streams pp2[j]
//    (float4 coalesced, L2, unroll-4 independent) over the block's 2048-j
//    half; one load tests BOTH rows (d2' = |dp*PSC|^2 <= 45, ~4% group-iter
//    hit rate); hits: exact fp32 feature dot -> fd', ep -> sp/t. Self-pair
//    at d2=0 -> sp>=1. Dropped pairs: ep < 2^-45, invisible in fp32.
//  k2: combine jh-planes, ce + reg -> out.
//
// ws (floats): n1n[0,8192) n2p[8192,16384) pp2[16384,49152)
// fragB[49152,180224) fragA[180224,311296) regp[311296,319488)
// sfp[319488,335872) spP[335872,352256) tP[352256,368640).

#define NPTS 4096
#define ROWS_TOT 8192
#define DF 32

#define L2E  1.4426950408889634f
#define LN2  0.6931471805599453f
#define FSC  1.6986436f          // sqrt(2*log2e)
#define PSC  240.2244f           // 200*sqrt(log2e)
#define D2MAX 45.0f              // keep pairs with log2e*(d/sigma)^2 <= 45

typedef _Float16 half8 __attribute__((ext_vector_type(8)));
typedef float f4 __attribute__((ext_vector_type(4)));

// ---- kA: prep ----
__global__ void kA_prep(const float* __restrict__ pts,
                        const float* __restrict__ f1g,
                        const float* __restrict__ f2g,
                        float* __restrict__ n1n, float* __restrict__ n2p,
                        float* __restrict__ pp2,
                        _Float16* __restrict__ fragA, _Float16* __restrict__ fragB,
                        float* __restrict__ regp, float* __restrict__ out) {
    const int r = blockIdx.x * 64 + threadIdx.x;     // 0..8191
    if (r < 4) out[r] = 0.0f;
    const int jt = r >> 4;                           // global tile id 0..511
    const int c  = r & 15;                           // row/col within tile

    float n1, n2, reg1, reg2;
    {
        const float4* f2v = (const float4*)(f2g + (size_t)r * DF);
        float vals[32]; float s = 0.0f;
#pragma unroll
        for (int q = 0; q < 8; ++q) {
            float4 v = f2v[q];
            vals[4*q]=v.x; vals[4*q+1]=v.y; vals[4*q+2]=v.z; vals[4*q+3]=v.w;
            s += v.x*v.x + v.y*v.y + v.z*v.z + v.w*v.w;
        }
        n2 = s;
        reg2 = s - vals[0]*vals[0] - vals[1]*vals[1] - vals[2]*vals[2];
        half8* fv = (half8*)fragB;
#pragma unroll
        for (int kb = 0; kb < 4; ++kb) {             // lane-ordered slot
            half8 h;
#pragma unroll
            for (int i = 0; i < 8; ++i) h[i] = (_Float16)(vals[kb*8+i] * FSC);
            fv[(size_t)jt*64 + kb*16 + c] = h;
        }
    }
    {
        const float4* f1v = (const float4*)(f1g + (size_t)r * DF);
        float vals[32]; float s = 0.0f;
#pragma unroll
        for (int q = 0; q < 8; ++q) {
            float4 v = f1v[q];
            vals[4*q]=v.x; vals[4*q+1]=v.y; vals[4*q+2]=v.z; vals[4*q+3]=v.w;
            s += v.x*v.x + v.y*v.y + v.z*v.z + v.w*v.w;
        }
        n1 = s;
        reg1 = s - vals[0]*vals[0] - vals[1]*vals[1] - vals[2]*vals[2];
        half8* fv = (half8*)fragA;
#pragma unroll
        for (int kb = 0; kb < 4; ++kb) {
            half8 h;
#pragma unroll
            for (int i = 0; i < 8; ++i) h[i] = (_Float16)(vals[kb*8+i] * FSC);
            fv[(size_t)jt*64 + kb*16 + c] = h;
        }
    }
    const float* pp = pts + (size_t)r * 3;
    n1n[r] = -(n1 * L2E);
    n2p[r] =  (n2 * L2E);
    ((float4*)pp2)[r] = make_float4(pp[0]*PSC, pp[1]*PSC, pp[2]*PSC, n2 * L2E);
    regp[r] = reg1 + reg2;
}

// ---- kB: phase1 dense feature MFMA; phase2 throughput point scan ----
__launch_bounds__(512)
__global__ void kB_main(const float* __restrict__ n1n,
                        const float* __restrict__ n2p,
                        const float* __restrict__ pp2,
                        const float* __restrict__ f1g,
                        const float* __restrict__ f2g,
                        const _Float16* __restrict__ fragA,
                        const _Float16* __restrict__ fragB,
                        float* __restrict__ sfp,
                        float* __restrict__ spP, float* __restrict__ tP) {
    __shared__ float sF[8][32];

    const int tid = threadIdx.x;
    const int l = tid & 63, wv = tid >> 6;           // wave 0..7
    const int ip = blockIdx.x >> 1;                  // i-pair 0..255
    const int jh = blockIdx.x & 1;                   // j-half 0/1
    const int b  = ip >> 7;
    const int i0g = ip * 32;
    const int lr = l & 15, lk = l >> 4;

    // ================= phase 1: feature path (proven loop) =================
    {
        const half8 afA = ((const half8*)fragA)[(size_t)(ip * 2)     * 64 + l];
        const half8 afB = ((const half8*)fragA)[(size_t)(ip * 2 + 1) * 64 + l];

        const int rbA = i0g + lk * 4;
        const int rbB = i0g + 16 + lk * 4;
        f4 qwA, qwB;                                 // -n1' per row
#pragma unroll
        for (int e = 0; e < 4; ++e) {
            qwA[e] = n1n[rbA + e];
            qwB[e] = n1n[rbB + e];
        }

        const int jt0 = b * 256 + jh * 128 + wv * 16;
        const int j0  = b * NPTS + jh * 2048 + wv * 256 + lr;
        const half8* fbase = (const half8*)fragB + ((size_t)jt0 * 64 + l);
        const float* nbase = n2p + j0;

        f4 sfA = {0,0,0,0}, sfB = {0,0,0,0};

        half8 bfC = fbase[0];
        float n2C = nbase[0];
#pragma unroll
        for (int t = 0; t < 16; ++t) {
            half8 bfN = bfC;
            float n2N = n2C;
            if (t < 15) {                            // 1-deep prefetch
                bfN = fbase[(t + 1) * 64];
                n2N = nbase[(t + 1) * 16];
            }
            const f4 C1A = qwA - n2C;                // -(n1'+n2')
            const f4 C1B = qwB - n2C;
            const f4 fdA = __builtin_amdgcn_mfma_f32_16x16x32_f16(afA, bfC, C1A, 0, 0, 0);
            const f4 fdB = __builtin_amdgcn_mfma_f32_16x16x32_f16(afB, bfC, C1B, 0, 0, 0);
#pragma unroll
            for (int e = 0; e < 4; ++e) {
                sfA[e] += __builtin_amdgcn_exp2f(fdA[e]);
                sfB[e] += __builtin_amdgcn_exp2f(fdB[e]);
            }
            bfC = bfN;
            n2C = n2N;
        }

#pragma unroll
        for (int m = 1; m < 16; m <<= 1) {
#pragma unroll
            for (int e = 0; e < 4; ++e) {
                sfA[e] += __shfl_xor(sfA[e], m);
                sfB[e] += __shfl_xor(sfB[e], m);
            }
        }
        if (lr == 0) {
#pragma unroll
            for (int e = 0; e < 4; ++e) {
                sF[wv][lk * 4 + e]      = sfA[e];
                sF[wv][16 + lk * 4 + e] = sfB[e];
            }
        }
    }
    __syncthreads();
    if (tid < 32) {
        float sf_ = 0.f;
#pragma unroll
        for (int w = 0; w < 8; ++w) sf_ += sF[w][tid];
        sfp[(size_t)jh * ROWS_TOT + i0g + tid] = sf_;
    }

    // ================= phase 2: point scan (throughput form) =================
    const int g   = tid >> 5;                        // group 0..15
    const int sub = tid & 31;
    const int r0  = i0g + g * 2, r1 = r0 + 1;
    const float4 q0 = ((const float4*)pp2)[r0];
    const float4 q1 = ((const float4*)pp2)[r1];
    const float n1r0 = n1n[r0], n1r1 = n1n[r1];
    const int jbase = b * NPTS + jh * 2048;
    const float4* pv = (const float4*)pp2 + jbase;
    const float4* f1v0 = (const float4*)(f1g + (size_t)r0 * DF);
    const float4* f1v1 = (const float4*)(f1g + (size_t)r1 * DF);

    float sp0 = 0.f, tt0 = 0.f, sp1 = 0.f, tt1 = 0.f;
#pragma unroll 4
    for (int k = 0; k < 64; ++k) {
        const int jj = sub + k * 32;                 // 0..2047
        const float4 v = pv[jj];
        const float dx0 = q0.x - v.x, dy0 = q0.y - v.y, dz0 = q0.z - v.z;
        const float dx1 = q1.x - v.x, dy1 = q1.y - v.y, dz1 = q1.z - v.z;
        const float d20 = fmaf(dx0, dx0, fmaf(dy0, dy0, dz0 * dz0));
        const float d21 = fmaf(dx1, dx1, fmaf(dy1, dy1, dz1 * dz1));
        if (d20 <= D2MAX) {                          // rare (incl. self)
            const float ep = __builtin_amdgcn_exp2f(-d20);
            const float4* f2v = (const float4*)(f2g + (size_t)(jbase + jj) * DF);
            float dot = 0.0f;
#pragma unroll
            for (int qq = 0; qq < 8; ++qq) {
                const float4 a = f1v0[qq], c = f2v[qq];
                dot += a.x*c.x + a.y*c.y + a.z*c.z + a.w*c.w;
            }
            const float fd = fmaf(2.0f * L2E, dot, n1r0 - v.w);
            sp0 += ep;
            tt0 = fmaf(ep, fd, tt0);
        }
        if (d21 <= D2MAX) {
            const float ep = __builtin_amdgcn_exp2f(-d21);
            const float4* f2v = (const float4*)(f2g + (size_t)(jbase + jj) * DF);
            float dot = 0.0f;
#pragma unroll
            for (int qq = 0; qq < 8; ++qq) {
                const float4 a = f1v1[qq], c = f2v[qq];
                dot += a.x*c.x + a.y*c.y + a.z*c.z + a.w*c.w;
            }
            const float fd = fmaf(2.0f * L2E, dot, n1r1 - v.w);
            sp1 += ep;
            tt1 = fmaf(ep, fd, tt1);
        }
    }

#pragma unroll
    for (int m = 1; m < 32; m <<= 1) {
        sp0 += __shfl_xor(sp0, m, 32);
        tt0 += __shfl_xor(tt0, m, 32);
        sp1 += __shfl_xor(sp1, m, 32);
        tt1 += __shfl_xor(tt1, m, 32);
    }
    if (sub == 0) {
        spP[(size_t)jh * ROWS_TOT + r0] = sp0;
        tP [(size_t)jh * ROWS_TOT + r0] = tt0;
        spP[(size_t)jh * ROWS_TOT + r1] = sp1;
        tP [(size_t)jh * ROWS_TOT + r1] = tt1;
    }
}

// ---- k2: combine jh planes, ce + reg -> out ----
__global__ void k2_final(const float* __restrict__ sfp,
                         const float* __restrict__ spP,
                         const float* __restrict__ tP,
                         const float* __restrict__ regp,
                         const float* __restrict__ wg,
                         float* __restrict__ out) {
    __shared__ float redc[4], redr[4];
    const int tid = threadIdx.x;
    const int r = blockIdx.x * 256 + tid;
    const int b = r >> 12;

    const float sf_ = sfp[r] + sfp[ROWS_TOT + r];
    const float sp_ = spP[r] + spP[ROWS_TOT + r];
    const float tp_ = tP[r]  + tP[ROWS_TOT + r];
    const float ce = __logf(sf_) - (tp_ * LN2) / sp_;
    float contrib = wg[r] * ce;
    float rr = regp[r];

#pragma unroll
    for (int off = 32; off > 0; off >>= 1) {
        contrib += __shfl_down(contrib, off);
        rr      += __shfl_down(rr, off);
    }
    const int wave = tid >> 6, lane = tid & 63;
    if (lane == 0) { redc[wave] = contrib; redr[wave] = rr; }
    __syncthreads();
    if (tid == 0) {
        atomicAdd(&out[b],     redc[0] + redc[1] + redc[2] + redc[3]);
        atomicAdd(&out[2 + b], (redr[0] + redr[1] + redr[2] + redr[3])
                               * (1.0f / (29.0f * (float)NPTS)));
    }
}

extern "C" void kernel_launch(void* const* d_in, const int* in_sizes, int n_in,
                              void* d_out, int out_size, void* d_ws, size_t ws_size,
                              hipStream_t stream) {
    const float* pts = (const float*)d_in[0];
    const float* f1  = (const float*)d_in[1];
    const float* f2  = (const float*)d_in[2];
    const float* wg  = (const float*)d_in[3];
    float* out = (float*)d_out;

    float* ws = (float*)d_ws;
    float*     n1n   = ws;                           // 8192
    float*     n2p   = ws + 8192;                    // 8192
    float*     pp2   = ws + 16384;                   // 32768 (float4 x 8192)
    _Float16*  fragB = (_Float16*)(ws + 49152);      // 262144 halves
    _Float16*  fragA = (_Float16*)(ws + 180224);     // 262144 halves
    float*     regp  = ws + 311296;                  // 8192
    float*     sfp   = ws + 319488;                  // 16384
    float*     spP   = ws + 335872;                  // 16384
    float*     tP    = ws + 352256;                  // 16384

    kA_prep<<<ROWS_TOT / 64, 64, 0, stream>>>(pts, f1, f2, n1n, n2p, pp2,
                                              fragA, fragB, regp, out);
    kB_main<<<512, 512, 0, stream>>>(n1n, n2p, pp2, f1, f2,
                                     fragA, fragB, sfp, spP, tP);
    k2_final<<<ROWS_TOT / 256, 256, 0, stream>>>(sfp, spP, tP, regp, wg, out);
}

// Round 18
// 25.038 us; speedup vs baseline: 2.3497x; 1.6050x over previous
//
#include <hip/hip_runtime.h>
#include <math.h>

// DeepFeatureLoss: B=2, N=4096, D=32, fp32 in/out.
// out[0..1] = ce_loss[b], out[2..3] = reg_loss[b].
//
// ce_i = log(s_f) - t/s_p  (softmax max pinned at 0; dists <= 0):
//   s_p = sum_j exp(pd_ij), t = sum_j exp(pd_ij)*fd_ij, s_f = sum_j exp(fd_ij)
// exp2 units; t *= LN2 at finalize.
//
// R18 = R12 (best, 28.5us, issue-bound at ~1GHz effective) + ONE change:
// point path VALU block (6 f4 ops + masked exps) -> 2nd C-folded MFMA with
// hi/lo f16 point fragments (12ch; R9-validated math). Frags combined per
// tile (128 half8: [0,64) feature, [64,128) point) -> B-stream stays one
// sequential walk; norms = one float2. Per-iter issue ~300 -> ~176 cyc.
//
// ws (floats): nrm1[0,16384) nrm2[16384,32768) fragB[32768,294912)
// fragA[294912,557056) regp[557056,565248) part[565248,614400).

#define NPTS 4096
#define ROWS_TOT 8192
#define DF 32

#define L2E  1.4426950408889634f
#define LN2  0.6931471805599453f
#define FSC  1.6986436f           // sqrt(2*log2e)
#define PSC2 339.72872f           // 200*sqrt(2*log2e)

typedef _Float16 half8 __attribute__((ext_vector_type(8)));
typedef float f4 __attribute__((ext_vector_type(4)));

// ---- kA: combined fragments (feature + hi/lo point) + norm float2s ----
__global__ void kA_prep(const float* __restrict__ pts,
                        const float* __restrict__ f1g,
                        const float* __restrict__ f2g,
                        float2* __restrict__ nrm1, float2* __restrict__ nrm2,
                        _Float16* __restrict__ fragA, _Float16* __restrict__ fragB,
                        float* __restrict__ regp, float* __restrict__ out) {
    const int r = blockIdx.x * 64 + threadIdx.x;     // 0..8191
    if (r < 4) out[r] = 0.0f;
    const int jt = r >> 4;                           // global tile id 0..511
    const int c  = r & 15;                           // row/col within tile

    float n1, n2, reg1, reg2;
    {   // features -> [0,64) of tile block
        const float4* f2v = (const float4*)(f2g + (size_t)r * DF);
        float vals[32]; float s = 0.0f;
#pragma unroll
        for (int q = 0; q < 8; ++q) {
            float4 v = f2v[q];
            vals[4*q]=v.x; vals[4*q+1]=v.y; vals[4*q+2]=v.z; vals[4*q+3]=v.w;
            s += v.x*v.x + v.y*v.y + v.z*v.z + v.w*v.w;
        }
        n2 = s;
        reg2 = s - vals[0]*vals[0] - vals[1]*vals[1] - vals[2]*vals[2];
        half8* fv = (half8*)fragB;
#pragma unroll
        for (int kb = 0; kb < 4; ++kb) {
            half8 h;
#pragma unroll
            for (int i = 0; i < 8; ++i) h[i] = (_Float16)(vals[kb*8+i] * FSC);
            fv[(size_t)jt*128 + kb*16 + c] = h;
        }
    }
    {
        const float4* f1v = (const float4*)(f1g + (size_t)r * DF);
        float vals[32]; float s = 0.0f;
#pragma unroll
        for (int q = 0; q < 8; ++q) {
            float4 v = f1v[q];
            vals[4*q]=v.x; vals[4*q+1]=v.y; vals[4*q+2]=v.z; vals[4*q+3]=v.w;
            s += v.x*v.x + v.y*v.y + v.z*v.z + v.w*v.w;
        }
        n1 = s;
        reg1 = s - vals[0]*vals[0] - vals[1]*vals[1] - vals[2]*vals[2];
        half8* fv = (half8*)fragA;
#pragma unroll
        for (int kb = 0; kb < 4; ++kb) {
            half8 h;
#pragma unroll
            for (int i = 0; i < 8; ++i) h[i] = (_Float16)(vals[kb*8+i] * FSC);
            fv[(size_t)jt*128 + kb*16 + c] = h;
        }
    }
    {   // points hi/lo -> [64,128) of tile block
        const float* pp = pts + (size_t)r * 3;
        const float v0 = pp[0]*PSC2, v1 = pp[1]*PSC2, v2 = pp[2]*PSC2;
        const float h0 = (float)(_Float16)v0, h1 = (float)(_Float16)v1,
                    h2 = (float)(_Float16)v2;
        const float l0 = v0 - h0, l1 = v1 - h1, l2 = v2 - h2;
        const float np = 0.5f * (v0*v0 + v1*v1 + v2*v2);

        // A ch0-11 = [h0,h1,h2,h0,h1,h2,l0,l1,l2,l0,l1,l2]
        // B ch0-11 = [h0,h1,h2,l0,l1,l2,h0,h1,h2,l0,l1,l2]
        const float pa[16] = {h0,h1,h2,h0,h1,h2,l0,l1,  l2,l0,l1,l2,0,0,0,0};
        const float pb[16] = {h0,h1,h2,l0,l1,l2,h0,h1,  h2,l0,l1,l2,0,0,0,0};
        half8* fa = (half8*)fragA;
        half8* fb = (half8*)fragB;
#pragma unroll
        for (int kb = 0; kb < 2; ++kb) {
            half8 ha, hb;
#pragma unroll
            for (int i = 0; i < 8; ++i) {
                ha[i] = (_Float16)pa[kb*8+i];
                hb[i] = (_Float16)pb[kb*8+i];
            }
            fa[(size_t)jt*128 + 64 + kb*16 + c] = ha;
            fb[(size_t)jt*128 + 64 + kb*16 + c] = hb;
        }
        const half8 z = {0,0,0,0,0,0,0,0};
        fa[(size_t)jt*128 + 64 + 32 + c] = z;  fa[(size_t)jt*128 + 64 + 48 + c] = z;
        fb[(size_t)jt*128 + 64 + 32 + c] = z;  fb[(size_t)jt*128 + 64 + 48 + c] = z;

        nrm1[r] = make_float2(-(n1 * L2E), -np);     // row side (negated)
        nrm2[r] = make_float2(  n2 * L2E,   np);     // col side (positive)
    }
    regp[r] = reg1 + reg2;
}

// ---- kB: MI=2; per iter: 2 frag loads + 1 float2 + 4 MFMA + 16 exp2 ----
__launch_bounds__(512)
__global__ void kB_main(const float2* __restrict__ nrm1,
                        const float2* __restrict__ nrm2,
                        const _Float16* __restrict__ fragA,
                        const _Float16* __restrict__ fragB,
                        float* __restrict__ part) {
    __shared__ float sS[8][32], sT[8][32], sF[8][32];

    const int tid = threadIdx.x;
    const int l = tid & 63, wv = tid >> 6;           // wave 0..7
    const int ip = blockIdx.x >> 1;                  // i-pair 0..255
    const int jh = blockIdx.x & 1;                   // j-half 0/1
    const int b  = ip >> 7;
    const int i0g = ip * 32;
    const int lr = l & 15, lk = l >> 4;

    // A fragments (feature + point) for both i-tiles
    const half8 afFA = ((const half8*)fragA)[(size_t)(ip*2)   * 128 + l];
    const half8 afPA = ((const half8*)fragA)[(size_t)(ip*2)   * 128 + 64 + l];
    const half8 afFB = ((const half8*)fragA)[(size_t)(ip*2+1) * 128 + l];
    const half8 afPB = ((const half8*)fragA)[(size_t)(ip*2+1) * 128 + 64 + l];

    const int rbA = i0g + lk * 4;
    const int rbB = i0g + 16 + lk * 4;
    f4 qfA, qpA, qfB, qpB;                           // -nf1', -np1' per row
#pragma unroll
    for (int e = 0; e < 4; ++e) {
        const float2 a = nrm1[rbA + e];
        const float2 bq = nrm1[rbB + e];
        qfA[e] = a.x;  qpA[e] = a.y;
        qfB[e] = bq.x; qpB[e] = bq.y;
    }

    const int jt0 = b * 256 + jh * 128 + wv * 16;
    const int j0  = b * NPTS + jh * 2048 + wv * 256 + lr;
    const half8*  fbase = (const half8*)fragB + ((size_t)jt0 * 128 + l);
    const float2* nbase = nrm2 + j0;

    f4 spA = {0,0,0,0}, tAA = {0,0,0,0}, sfA = {0,0,0,0};
    f4 spB = {0,0,0,0}, tAB = {0,0,0,0}, sfB = {0,0,0,0};

    half8  bfFC = fbase[0];
    half8  bfPC = fbase[64];
    float2 nwC  = nbase[0];
#pragma unroll
    for (int t = 0; t < 16; ++t) {
        half8 bfFN = bfFC, bfPN = bfPC;
        float2 nwN = nwC;
        if (t < 15) {                                // 1-deep prefetch
            bfFN = fbase[(t + 1) * 128];
            bfPN = fbase[(t + 1) * 128 + 64];
            nwN  = nbase[(t + 1) * 16];
        }
        // tile A
        {
            const f4 C1 = qfA - nwC.x;               // -(nf1'+nf2')
            const f4 C2 = qpA - nwC.y;               // -(np1'+np2')
            const f4 fd = __builtin_amdgcn_mfma_f32_16x16x32_f16(afFA, bfFC, C1, 0, 0, 0);
            const f4 pd = __builtin_amdgcn_mfma_f32_16x16x32_f16(afPA, bfPC, C2, 0, 0, 0);
            f4 ep, ef;
#pragma unroll
            for (int e = 0; e < 4; ++e) {
                ep[e] = __builtin_amdgcn_exp2f(pd[e]);
                ef[e] = __builtin_amdgcn_exp2f(fd[e]);
            }
            spA += ep; tAA += ep * fd; sfA += ef;
        }
        // tile B
        {
            const f4 C1 = qfB - nwC.x;
            const f4 C2 = qpB - nwC.y;
            const f4 fd = __builtin_amdgcn_mfma_f32_16x16x32_f16(afFB, bfFC, C1, 0, 0, 0);
            const f4 pd = __builtin_amdgcn_mfma_f32_16x16x32_f16(afPB, bfPC, C2, 0, 0, 0);
            f4 ep, ef;
#pragma unroll
            for (int e = 0; e < 4; ++e) {
                ep[e] = __builtin_amdgcn_exp2f(pd[e]);
                ef[e] = __builtin_amdgcn_exp2f(fd[e]);
            }
            spB += ep; tAB += ep * fd; sfB += ef;
        }
        bfFC = bfFN; bfPC = bfPN; nwC = nwN;
    }

    // reduce over the 16 columns (lane bits 0..3), both tiles
#pragma unroll
    for (int m = 1; m < 16; m <<= 1) {
#pragma unroll
        for (int e = 0; e < 4; ++e) {
            spA[e] += __shfl_xor(spA[e], m);
            tAA[e] += __shfl_xor(tAA[e], m);
            sfA[e] += __shfl_xor(sfA[e], m);
            spB[e] += __shfl_xor(spB[e], m);
            tAB[e] += __shfl_xor(tAB[e], m);
            sfB[e] += __shfl_xor(sfB[e], m);
        }
    }
    if (lr == 0) {
#pragma unroll
        for (int e = 0; e < 4; ++e) {
            sS[wv][lk * 4 + e]      = spA[e];
            sT[wv][lk * 4 + e]      = tAA[e];
            sF[wv][lk * 4 + e]      = sfA[e];
            sS[wv][16 + lk * 4 + e] = spB[e];
            sT[wv][16 + lk * 4 + e] = tAB[e];
            sF[wv][16 + lk * 4 + e] = sfB[e];
        }
    }
    __syncthreads();

    if (tid < 32) {
        float sp_ = 0.f, tp_ = 0.f, sf_ = 0.f;
#pragma unroll
        for (int w = 0; w < 8; ++w) {
            sp_ += sS[w][tid];
            tp_ += sT[w][tid];
            sf_ += sF[w][tid];
        }
        float* P = part + (size_t)jh * 3 * ROWS_TOT;
        P[i0g + tid]                = sp_;
        P[ROWS_TOT + i0g + tid]     = tp_;
        P[2 * ROWS_TOT + i0g + tid] = sf_;
    }
}

// ---- k2: combine 2 j-half planes, ce + reg -> out ----
__global__ void k2_final(const float* __restrict__ part,
                         const float* __restrict__ regp,
                         const float* __restrict__ wg,
                         float* __restrict__ out) {
    __shared__ float redc[4], redr[4];
    const int tid = threadIdx.x;
    const int r = blockIdx.x * 256 + tid;
    const int b = r >> 12;

    const float* P0 = part;
    const float* P1 = part + (size_t)3 * ROWS_TOT;
    const float sp_ = P0[r] + P1[r];
    const float tp_ = P0[ROWS_TOT + r] + P1[ROWS_TOT + r];
    const float sf_ = P0[2*ROWS_TOT + r] + P1[2*ROWS_TOT + r];
    const float ce = __logf(sf_) - (tp_ * LN2) / sp_;
    float contrib = wg[r] * ce;
    float rr = regp[r];

#pragma unroll
    for (int off = 32; off > 0; off >>= 1) {
        contrib += __shfl_down(contrib, off);
        rr      += __shfl_down(rr, off);
    }
    const int wave = tid >> 6, lane = tid & 63;
    if (lane == 0) { redc[wave] = contrib; redr[wave] = rr; }
    __syncthreads();
    if (tid == 0) {
        atomicAdd(&out[b],     redc[0] + redc[1] + redc[2] + redc[3]);
        atomicAdd(&out[2 + b], (redr[0] + redr[1] + redr[2] + redr[3])
                               * (1.0f / (29.0f * (float)NPTS)));
    }
}

extern "C" void kernel_launch(void* const* d_in, const int* in_sizes, int n_in,
                              void* d_out, int out_size, void* d_ws, size_t ws_size,
                              hipStream_t stream) {
    const float* pts = (const float*)d_in[0];
    const float* f1  = (const float*)d_in[1];
    const float* f2  = (const float*)d_in[2];
    const float* wg  = (const float*)d_in[3];
    float* out = (float*)d_out;

    float* ws = (float*)d_ws;
    float2*    nrm1  = (float2*)ws;                  // 8192 float2
    float2*    nrm2  = (float2*)(ws + 16384);        // 8192 float2
    _Float16*  fragB = (_Float16*)(ws + 32768);      // 524288 halves
    _Float16*  fragA = (_Float16*)(ws + 294912);     // 524288 halves
    float*     regp  = ws + 557056;                  // 8192
    float*     part  = ws + 565248;                  // 2*3*8192

    kA_prep<<<ROWS_TOT / 64, 64, 0, stream>>>(pts, f1, f2, nrm1, nrm2,
                                              fragA, fragB, regp, out);
    kB_main<<<512, 512, 0, stream>>>(nrm1, nrm2, fragA, fragB, part);
    k2_final<<<ROWS_TOT / 256, 256, 0, stream>>>(part, regp, wg, out);
}